// Round 5
// baseline (737.014 us; speedup 1.0000x reference)
//
#include <hip/hip_runtime.h>

#define BATCH   2048
#define DIM     512
#define DB_N    50000
#define TOPK    5
#define PADN    50176       // 392 tiles of 128
#define NCHUNK  32
#define TM      128
#define TN      128
#define NFIN    12

typedef float f32x4 __attribute__((ext_vector_type(4)));
typedef long long i64;

__device__ __forceinline__ void async16(const void* g, void* l) {
    __builtin_amdgcn_global_load_lds(
        (const __attribute__((address_space(1))) unsigned int*)g,
        (__attribute__((address_space(3))) unsigned int*)l, 16, 0, 0);
}

__device__ __forceinline__ short f2bf(float f) {
    union { float f; unsigned u; } v; v.f = f;
    unsigned r = v.u + 0x7FFFu + ((v.u >> 16) & 1u);
    return (short)(r >> 16);
}

// ============ convert: L2-normalize, scale x16, fp8 e4m3, k-chunk + unit-swizzle ============
// dst byte ((kb*NROWS + r)*64) + ((w ^ ((r>>1)&7))<<3) holds row r, k in [kb*64 + w*8, +8).
// Linear 16B DMA preserves bytes; ds_read applies the same XOR to recover k-order.
template<int NROWS>
__global__ void convert_kernel(const float* __restrict__ src, unsigned char* __restrict__ dst,
                               float* __restrict__ invp, int nreal) {
    const int r    = blockIdx.x * 4 + (threadIdx.x >> 6);
    const int lane = threadIdx.x & 63;
    float4 a = {0,0,0,0}, b = {0,0,0,0};
    float ss = 0.f;
    if (r < nreal) {
        const float* row = src + (size_t)r * DIM;
        a = *(const float4*)(row + lane * 8);
        b = *(const float4*)(row + lane * 8 + 4);
        ss = a.x*a.x + a.y*a.y + a.z*a.z + a.w*a.w
           + b.x*b.x + b.y*b.y + b.z*b.z + b.w*b.w;
    }
    #pragma unroll
    for (int off = 1; off < 64; off <<= 1) ss += __shfl_xor(ss, off);
    const float inv = 1.0f / fmaxf(sqrtf(ss), 1e-12f);
    const float s16 = inv * 16.0f;
    int lo = __builtin_amdgcn_cvt_pk_fp8_f32(a.x * s16, a.y * s16, 0, false);
    lo     = __builtin_amdgcn_cvt_pk_fp8_f32(a.z * s16, a.w * s16, lo, true);
    int hi = __builtin_amdgcn_cvt_pk_fp8_f32(b.x * s16, b.y * s16, 0, false);
    hi     = __builtin_amdgcn_cvt_pk_fp8_f32(b.z * s16, b.w * s16, hi, true);
    const int kb = lane >> 3;
    const int w  = lane & 7;
    int2 u; u.x = lo; u.y = hi;
    *(int2*)(dst + ((size_t)kb * NROWS + r) * 64 + ((w ^ ((r >> 1) & 7)) << 3)) = u;
    if (invp && lane == 0) invp[r] = inv;
}

// ============ fused sim GEMM (fp8, 128x128, 8 waves 2Mx4N, 4x2 frags) + top-5 ============
__global__ __launch_bounds__(512, 4) void sim_topk_kernel(
    const unsigned char* __restrict__ hzf, const unsigned char* __restrict__ dbzf,
    unsigned* __restrict__ pc) {

    __shared__ __align__(16) unsigned char As[2][TM * 64];   // 2 x 8KB
    __shared__ __align__(16) unsigned char Bs[2][TN * 64];   // 2 x 8KB
    __shared__ unsigned mrg[2][4][64][TOPK];                 // 10KB

    const int tid  = threadIdx.x;
    const int lane = tid & 63;
    const int l15  = lane & 15;
    const int lhi  = lane >> 4;
    const int wid  = tid >> 6;
    const int uw   = __builtin_amdgcn_readfirstlane(wid);   // wave-uniform (SGPR) wave id
    const int wm   = wid >> 2;            // 0..1
    const int wn   = wid & 3;             // 0..3
    const int rb   = blockIdx.x >> 5;     // 0..15 (batch block of 128)
    const int mc   = blockIdx.x & 31;     // 0..31 chunk; siblings share XCD (bid%8==mc%8)
    const int ts   = mc * 12 + (mc < 8 ? mc : 8);
    const int te   = ts + 12 + (mc < 8 ? 1 : 0);

    // each lane owns ONE row of its wave's 64-row half: (mf,i) = (l15>>2, l15&3)
    float tv[TOPK]; int ti[TOPK];
    #pragma unroll
    for (int j = 0; j < TOPK; ++j) { tv[j] = -3.0e38f; ti[j] = 0; }

    // wave-uniform LDS dest (base + lane*16 implicit); per-lane global src
    auto STAGE = [&](int buf, int t, int kb) {
        const unsigned char* ga = hzf + ((size_t)kb * BATCH + (size_t)rb * TM) * 64
                                + uw * 1024 + lane * 16;
        const unsigned char* gb = dbzf + ((size_t)kb * PADN + (size_t)t * TN) * 64
                                + uw * 1024 + lane * 16;
        async16(ga, &As[buf][uw * 1024]);
        async16(gb, &Bs[buf][uw * 1024]);
    };

    f32x4 acc[4][2];

    STAGE(0, ts, 0);
    __syncthreads();

    int p = 0;
    #pragma unroll 1
    for (int t = ts; t < te; ++t) {
        #pragma unroll
        for (int mf = 0; mf < 4; ++mf)
            #pragma unroll
            for (int nf = 0; nf < 2; ++nf) acc[mf][nf] = (f32x4){0.f, 0.f, 0.f, 0.f};

        #pragma unroll 1
        for (int kb = 0; kb < 8; ++kb) {
            const int nt2 = (kb == 7) ? t + 1 : t;
            if (nt2 < te) STAGE((p + 1) & 1, nt2, (kb + 1) & 7);

            const unsigned char* ta = As[p & 1];
            const unsigned char* tb = Bs[p & 1];
            #pragma unroll
            for (int ks = 0; ks < 2; ++ks) {
                const int swz = (ks * 32 + lhi * 8) ^ ((l15 & 14) << 2);
                i64 af[4], bf[2];
                #pragma unroll
                for (int mf = 0; mf < 4; ++mf)
                    af[mf] = *(const i64*)(ta + (wm * 64 + mf * 16 + l15) * 64 + swz);
                #pragma unroll
                for (int nf = 0; nf < 2; ++nf)
                    bf[nf] = *(const i64*)(tb + (wn * 32 + nf * 16 + l15) * 64 + swz);
                #pragma unroll
                for (int mf = 0; mf < 4; ++mf)
                    #pragma unroll
                    for (int nf = 0; nf < 2; ++nf)
                        acc[mf][nf] = __builtin_amdgcn_mfma_f32_16x16x32_fp8_fp8(
                            af[mf], bf[nf], acc[mf][nf], 0, 0, 0);
            }
            __syncthreads();
            ++p;
        }

        // ---- per-tile top-5 epilogue (compact; unroll 1 to keep I-footprint small) ----
        const int n0 = t * TN;
        if (n0 + TN > DB_N) {
            #pragma unroll
            for (int nf = 0; nf < 2; ++nf) {
                const bool valid = (n0 + wn * 32 + nf * 16 + l15) < DB_N;
                if (!valid) {
                    #pragma unroll
                    for (int mf = 0; mf < 4; ++mf)
                        #pragma unroll
                        for (int i = 0; i < 4; ++i) acc[mf][nf][i] = -3.0e38f;
                }
            }
        }
        #pragma unroll 1
        for (int mf = 0; mf < 4; ++mf) {
            #pragma unroll 1
            for (int i = 0; i < 4; ++i) {
                const int osrc = (lane & 48) + (mf << 2) + i;
                float thr = __shfl(tv[TOPK - 1], osrc, 64);
                float m = fmaxf(acc[mf][0][i], acc[mf][1][i]);
                #pragma unroll
                for (int sh = 1; sh < 16; sh <<= 1) m = fmaxf(m, __shfl_xor(m, sh));
                if (!__any(m > thr)) continue;
                #pragma unroll 1
                for (int it = 0; it < TOPK; ++it) {
                    float v = acc[mf][0][i]; int c = l15;
                    if (acc[mf][1][i] > v) { v = acc[mf][1][i]; c = 16 + l15; }
                    #pragma unroll
                    for (int sh = 1; sh < 16; sh <<= 1) {
                        const float ov = __shfl_xor(v, sh);
                        const int   oc = __shfl_xor(c, sh);
                        if (ov > v || (ov == v && oc < c)) { v = ov; c = oc; }
                    }
                    if (!__any(v > thr)) break;
                    const int gi = n0 + wn * 32 + c;
                    if (l15 == ((mf << 2) | i) && v > thr) {
                        #pragma unroll
                        for (int j = TOPK - 1; j >= 1; --j) {
                            const bool gt  = v > tv[j];
                            const bool gtp = v > tv[j - 1];
                            tv[j] = gt ? (gtp ? tv[j - 1] : v)  : tv[j];
                            ti[j] = gt ? (gtp ? ti[j - 1] : gi) : ti[j];
                        }
                        if (v > tv[0]) { tv[0] = v; ti[0] = gi; }
                    }
                    #pragma unroll
                    for (int nf = 0; nf < 2; ++nf)
                        if (nf * 16 + l15 == c) acc[mf][nf][i] = -3.0e38f;
                    thr = __shfl(tv[TOPK - 1], osrc, 64);
                }
            }
        }
    }

    // ---- merge the 4 wn-waves' per-row top-5 (they cover different col quarters) ----
    const int rl = (l15 >> 2) * 16 + lhi * 4 + (l15 & 3);   // my owned row in [0,64)
    #pragma unroll
    for (int j = 0; j < TOPK; ++j)
        mrg[wm][wn][rl][j] = (((unsigned)(unsigned short)f2bf(tv[j])) << 16) | (unsigned)ti[j];
    __syncthreads();
    if (wn == 0) {
        float bv[TOPK]; unsigned bu[TOPK];
        #pragma unroll
        for (int j = 0; j < TOPK; ++j) { bv[j] = -3.0e38f; bu[j] = 0; }
        #pragma unroll 1
        for (int q = 0; q < 4; ++q) {
            #pragma unroll
            for (int j = 0; j < TOPK; ++j) {
                const unsigned u = mrg[wm][q][rl][j];
                const float v = __uint_as_float(u & 0xFFFF0000u);
                #pragma unroll
                for (int k = TOPK - 1; k >= 1; --k) {
                    const bool gt  = v > bv[k];
                    const bool gtp = v > bv[k - 1];
                    bv[k] = gt ? (gtp ? bv[k - 1] : v) : bv[k];
                    bu[k] = gt ? (gtp ? bu[k - 1] : u) : bu[k];
                }
                if (v > bv[0]) { bv[0] = v; bu[0] = u; }
            }
        }
        const int row = rb * TM + wm * 64 + rl;
        const size_t base = ((size_t)row * NCHUNK + mc) * TOPK;
        #pragma unroll
        for (int j = 0; j < TOPK; ++j) pc[base + j] = bu[j];
    }
}

// ============ finalize: merge 160 -> top-12 (fp8 score), EXACT fp32 refine, top-5 ============
__global__ void finalize_kernel(const float* __restrict__ h, const float* __restrict__ db,
                                const float* __restrict__ alpha_p,
                                const unsigned* __restrict__ pc,
                                const float* __restrict__ inv_db,
                                float* __restrict__ out) {
    const int b    = blockIdx.x;
    const int tid  = threadIdx.x;
    const int lane = tid & 63;
    const int wv   = tid >> 6;
    const int NC   = NCHUNK * TOPK;   // 160

    __shared__ int   fid[NFIN];
    __shared__ float fsim[NFIN];
    __shared__ float invh_s;
    __shared__ float mu_s[TOPK];
    __shared__ int   id_s[TOPK];

    if (wv == 0) {
        const unsigned* cp = pc + (size_t)b * NC;
        float v[3]; int ix[3];
        #pragma unroll
        for (int j = 0; j < 3; ++j) {
            const int c  = lane + j * 64;
            const bool ok = c < NC;
            const unsigned u = ok ? cp[c] : 0u;
            v[j]  = ok ? __uint_as_float(u & 0xFFFF0000u) : -3.0e38f;
            ix[j] = ok ? (int)(u & 0xFFFFu) : 0x7fffffff;
        }
        for (int it = 0; it < NFIN; ++it) {
            float m = v[0]; int mi = ix[0];
            if (v[1] > m || (v[1] == m && ix[1] < mi)) { m = v[1]; mi = ix[1]; }
            if (v[2] > m || (v[2] == m && ix[2] < mi)) { m = v[2]; mi = ix[2]; }
            #pragma unroll
            for (int sh = 1; sh < 64; sh <<= 1) {
                const float om = __shfl_xor(m, sh);
                const int   oi = __shfl_xor(mi, sh);
                if (om > m || (om == m && oi < mi)) { m = om; mi = oi; }
            }
            if (lane == 0) fid[it] = mi;
            #pragma unroll
            for (int j = 0; j < 3; ++j) if (ix[j] == mi) v[j] = -3.0e38f;
        }
    } else if (wv == 1) {
        const float* hr = h + (size_t)b * DIM;
        const float4 a = *(const float4*)(hr + lane * 8);
        const float4 c = *(const float4*)(hr + lane * 8 + 4);
        float ss = a.x*a.x + a.y*a.y + a.z*a.z + a.w*a.w
                 + c.x*c.x + c.y*c.y + c.z*c.z + c.w*c.w;
        #pragma unroll
        for (int off = 1; off < 64; off <<= 1) ss += __shfl_xor(ss, off);
        if (lane == 0) invh_s = 1.0f / fmaxf(sqrtf(ss), 1e-12f);
    }
    __syncthreads();

    const float* hr = h + (size_t)b * DIM;
    for (int f = wv; f < NFIN; f += 4) {
        const int gi = fid[f];
        const float* dr = db + (size_t)gi * DIM;
        const float4 ha = *(const float4*)(hr + lane * 8);
        const float4 hb = *(const float4*)(hr + lane * 8 + 4);
        const float4 da = *(const float4*)(dr + lane * 8);
        const float4 dc = *(const float4*)(dr + lane * 8 + 4);
        float d = ha.x*da.x + ha.y*da.y + ha.z*da.z + ha.w*da.w
                + hb.x*dc.x + hb.y*dc.y + hb.z*dc.z + hb.w*dc.w;
        #pragma unroll
        for (int off = 1; off < 64; off <<= 1) d += __shfl_xor(d, off);
        if (lane == 0) fsim[f] = d * invh_s * inv_db[gi];
    }
    __syncthreads();

    if (tid == 0) {
        bool used[NFIN];
        #pragma unroll
        for (int j = 0; j < NFIN; ++j) used[j] = false;
        float bv[TOPK]; int bi[TOPK];
        for (int it = 0; it < TOPK; ++it) {
            float m = -3.0e38f; int mj = 0, mi = 0x7fffffff;
            for (int j = 0; j < NFIN; ++j) {
                if (used[j]) continue;
                if (fsim[j] > m || (fsim[j] == m && fid[j] < mi)) {
                    m = fsim[j]; mj = j; mi = fid[j];
                }
            }
            used[mj] = true; bv[it] = m; bi[it] = mi;
        }
        float ssum = 0.f, w[TOPK];
        #pragma unroll
        for (int j = 0; j < TOPK; ++j) { w[j] = expf(bv[j] - bv[0]); ssum += w[j]; }
        #pragma unroll
        for (int j = 0; j < TOPK; ++j) { mu_s[j] = w[j] / ssum; id_s[j] = bi[j]; }
    }
    __syncthreads();

    const float a = 1.0f / (1.0f + expf(-alpha_p[0]));
    for (int d = tid; d < DIM; d += 256) {
        float r = 0.f;
        #pragma unroll
        for (int j = 0; j < TOPK; ++j) r += mu_s[j] * db[(size_t)id_s[j] * DIM + d];
        out[(size_t)b * DIM + d] = a * h[(size_t)b * DIM + d] + (1.f - a) * r;
    }
}

extern "C" void kernel_launch(void* const* d_in, const int* in_sizes, int n_in,
                              void* d_out, int out_size, void* d_ws, size_t ws_size,
                              hipStream_t stream) {
    const float* h     = (const float*)d_in[0];
    const float* db    = (const float*)d_in[1];
    const float* alpha = (const float*)d_in[2];
    float* out = (float*)d_out;

    const size_t dbzf_bytes = (size_t)PADN * DIM;        // 25,690,112
    const size_t hzf_bytes  = (size_t)BATCH * DIM;       //  1,048,576
    const size_t inv_bytes  = (size_t)PADN * 4;          //    200,704

    unsigned char* dbzf   = (unsigned char*)d_ws;
    unsigned char* hzf    = (unsigned char*)d_ws + dbzf_bytes;
    float*         invdb  = (float*)((char*)d_ws + dbzf_bytes + hzf_bytes);
    unsigned*      pc     = (unsigned*)((char*)d_ws + dbzf_bytes + hzf_bytes + inv_bytes);

    convert_kernel<PADN><<<PADN / 4, 256, 0, stream>>>(db, dbzf, invdb, DB_N);
    convert_kernel<BATCH><<<BATCH / 4, 256, 0, stream>>>(h, hzf, nullptr, BATCH);
    sim_topk_kernel<<<16 * NCHUNK, 512, 0, stream>>>(hzf, dbzf, pc);
    finalize_kernel<<<BATCH, 256, 0, stream>>>(h, db, alpha, pc, invdb, out);
}

// Round 6
// 176.485 us; speedup vs baseline: 4.1761x; 4.1761x over previous
//
#include <hip/hip_runtime.h>

#define BATCH   2048
#define DIM     512
#define DB_N    50000
#define TOPK    5
#define PADN    50176       // 392 tiles of 128
#define NCHUNK  56          // 7 tiles (896 cols) per chunk; 56%8==0 -> chunk pins to one XCD
#define CTILES  7
#define CCOLS   896
#define TM      128
#define TN      128
#define NFIN    12

typedef float f32x4 __attribute__((ext_vector_type(4)));
typedef long long i64;

__device__ __forceinline__ void async16(const void* g, void* l) {
    __builtin_amdgcn_global_load_lds(
        (const __attribute__((address_space(1))) unsigned int*)g,
        (__attribute__((address_space(3))) unsigned int*)l, 16, 0, 0);
}

// monotone float -> u32 (order-preserving for all finite values)
__device__ __forceinline__ unsigned sortbits(float v) {
    const int u = __float_as_int(v);
    return (unsigned)(u ^ ((u >> 31) | 0x80000000));
}

// ============ convert: L2-normalize, scale x16, fp8 e4m3, k-chunk (BK=128) + 16B-unit swizzle ======
// row r, k-bytes [kb*128 + w*16, +16) stored at byte ((kb*NROWS + r)*8 + (w ^ (r&7)))*16.
// Linear 16B DMA preserves unit order; ds_read XORs the unit index to recover k-order.
template<int NROWS>
__global__ void convert_kernel(const float* __restrict__ src, unsigned char* __restrict__ dst,
                               float* __restrict__ invp, int nreal) {
    const int r    = blockIdx.x * 4 + (threadIdx.x >> 6);
    const int lane = threadIdx.x & 63;
    float4 a = {0,0,0,0}, b = {0,0,0,0};
    float ss = 0.f;
    if (r < nreal) {
        const float* row = src + (size_t)r * DIM;
        a = *(const float4*)(row + lane * 8);
        b = *(const float4*)(row + lane * 8 + 4);
        ss = a.x*a.x + a.y*a.y + a.z*a.z + a.w*a.w
           + b.x*b.x + b.y*b.y + b.z*b.z + b.w*b.w;
    }
    #pragma unroll
    for (int off = 1; off < 64; off <<= 1) ss += __shfl_xor(ss, off);
    const float inv = 1.0f / fmaxf(sqrtf(ss), 1e-12f);
    const float s16 = inv * 16.0f;
    int lo = __builtin_amdgcn_cvt_pk_fp8_f32(a.x * s16, a.y * s16, 0, false);
    lo     = __builtin_amdgcn_cvt_pk_fp8_f32(a.z * s16, a.w * s16, lo, true);
    int hi = __builtin_amdgcn_cvt_pk_fp8_f32(b.x * s16, b.y * s16, 0, false);
    hi     = __builtin_amdgcn_cvt_pk_fp8_f32(b.z * s16, b.w * s16, hi, true);
    // this lane covers k in [lane*8, +8): unit u = lane>>1, kb = u>>3, w = u&7
    const int kb = lane >> 4;
    const int w  = (lane >> 1) & 7;
    int2 u2; u2.x = lo; u2.y = hi;
    *(int2*)(dst + ((size_t)kb * NROWS + r) * 128 + ((w ^ (r & 7)) << 4) + ((lane & 1) << 3)) = u2;
    if (invp && lane == 0) invp[r] = inv;
}

// ============ fused sim GEMM (fp8, 128x128, BK=128, 8 waves 2Mx4N) + per-lane key top-2 ============
__global__ __launch_bounds__(512, 4) void sim_topk_kernel(
    const unsigned char* __restrict__ hzf, const unsigned char* __restrict__ dbzf,
    unsigned* __restrict__ pc) {

    __shared__ __align__(16) unsigned char As[2][TM * 128];   // 2 x 16KB
    __shared__ __align__(16) unsigned char Bs[2][TN * 128];   // 2 x 16KB
    __shared__ unsigned mrg[2][4][64][TOPK];                  // 10KB

    const int tid  = threadIdx.x;
    const int lane = tid & 63;
    const int l15  = lane & 15;
    const int lhi  = lane >> 4;
    const int wid  = tid >> 6;
    const int uw   = __builtin_amdgcn_readfirstlane(wid);
    const int wm   = wid >> 2;            // 0..1 (row half)
    const int wn   = wid & 3;             // 0..3 (col quarter)
    const int mc   = blockIdx.x % NCHUNK; // chunk; all rb-siblings share XCD (56%8==0)
    const int rb   = blockIdx.x / NCHUNK; // 0..15
    const int c0   = mc * CCOLS;

    // per-lane top-2 keys for each of this lane's 16 owned rows (q = mf*4+i)
    unsigned k0[16], k1[16];
    #pragma unroll
    for (int q = 0; q < 16; ++q) { k0[q] = 0u; k1[q] = 0u; }

    auto STAGE = [&](int buf, int t, int kb) {
        const unsigned char* ga = hzf +
            (((size_t)kb * BATCH + (size_t)rb * TM) * 8 + uw * 128 + lane) * 16;
        const unsigned char* gb = dbzf +
            (((size_t)kb * PADN + (size_t)(c0 + t * TN)) * 8 + uw * 128 + lane) * 16;
        async16(ga,        &As[buf][uw * 2048]);
        async16(ga + 1024, &As[buf][uw * 2048 + 1024]);
        async16(gb,        &Bs[buf][uw * 2048]);
        async16(gb + 1024, &Bs[buf][uw * 2048 + 1024]);
    };

    f32x4 acc[4][2];

    STAGE(0, 0, 0);
    __syncthreads();

    int p = 0;
    #pragma unroll 1
    for (int t = 0; t < CTILES; ++t) {
        #pragma unroll
        for (int mf = 0; mf < 4; ++mf)
            #pragma unroll
            for (int nf = 0; nf < 2; ++nf) acc[mf][nf] = (f32x4){0.f, 0.f, 0.f, 0.f};

        #pragma unroll
        for (int kb = 0; kb < 4; ++kb) {
            const int np = p + 1;
            if (np < CTILES * 4) STAGE(np & 1, np >> 2, np & 3);

            const unsigned char* ta = As[p & 1];
            const unsigned char* tb = Bs[p & 1];
            #pragma unroll
            for (int ks = 0; ks < 4; ++ks) {
                const int sub = ks * 2 + (lhi >> 1);     // desired 16B unit in row
                const int c8  = (lhi & 1) << 3;
                i64 af[4], bfr[2];
                #pragma unroll
                for (int mf = 0; mf < 4; ++mf) {
                    const int r = wm * 64 + mf * 16 + l15;
                    af[mf] = *(const i64*)(ta + r * 128 + ((sub ^ (r & 7)) << 4) + c8);
                }
                #pragma unroll
                for (int nf = 0; nf < 2; ++nf) {
                    const int r = wn * 32 + nf * 16 + l15;
                    bfr[nf] = *(const i64*)(tb + r * 128 + ((sub ^ (r & 7)) << 4) + c8);
                }
                #pragma unroll
                for (int mf = 0; mf < 4; ++mf)
                    #pragma unroll
                    for (int nf = 0; nf < 2; ++nf)
                        acc[mf][nf] = __builtin_amdgcn_mfma_f32_16x16x32_fp8_fp8(
                            af[mf], bfr[nf], acc[mf][nf], 0, 0, 0);
            }
            __syncthreads();
            ++p;
        }

        // ---- per-tile epilogue: branchless per-lane top-2 key update (no shuffles) ----
        const int tc = c0 + t * TN;
        #pragma unroll
        for (int nf = 0; nf < 2; ++nf) {
            const int  gcol  = tc + wn * 32 + nf * 16 + l15;
            const bool valid = gcol < DB_N;
            #pragma unroll
            for (int mf = 0; mf < 4; ++mf)
                #pragma unroll
                for (int i = 0; i < 4; ++i) {
                    const int q = mf * 4 + i;
                    const unsigned key = valid
                        ? ((sortbits(acc[mf][nf][i]) & 0xFFFF0000u) | (unsigned)gcol) : 0u;
                    const unsigned hi2 = key > k0[q] ? key   : k0[q];
                    const unsigned lo2 = key > k0[q] ? k0[q] : key;
                    k1[q] = lo2 > k1[q] ? lo2 : k1[q];
                    k0[q] = hi2;
                }
        }
    }

    // ---- once per chunk: per-row top-5 extract within each wave's col quarter ----
    #pragma unroll
    for (int mf = 0; mf < 4; ++mf)
        #pragma unroll
        for (int i = 0; i < 4; ++i) {
            const int q = mf * 4 + i;
            unsigned a0 = k0[q], a1 = k1[q];
            #pragma unroll
            for (int it = 0; it < TOPK; ++it) {
                unsigned w = a0;
                #pragma unroll
                for (int sh = 1; sh < 16; sh <<= 1) {
                    const unsigned o = (unsigned)__shfl_xor((int)w, sh);
                    w = o > w ? o : w;
                }
                const bool own = (a0 == w) && (w != 0u);
                a0 = own ? a1 : a0;
                a1 = own ? 0u : a1;
                if (l15 == q) mrg[wm][wn][mf * 16 + lhi * 4 + i][it] = w;
            }
        }
    __syncthreads();

    // ---- merge 4 col-quarters -> exact chunk top-5 per row; write packed keys ----
    if (wn == 0) {
        unsigned bv[TOPK] = {0u, 0u, 0u, 0u, 0u};
        #pragma unroll
        for (int qq = 0; qq < 4; ++qq)
            #pragma unroll
            for (int j = 0; j < TOPK; ++j) {
                const unsigned u = mrg[wm][qq][lane][j];
                #pragma unroll
                for (int k = TOPK - 1; k >= 1; --k) {
                    const bool gt  = u > bv[k];
                    const bool gtp = u > bv[k - 1];
                    bv[k] = gt ? (gtp ? bv[k - 1] : u) : bv[k];
                }
                if (u > bv[0]) bv[0] = u;
            }
        const int row = rb * TM + wm * 64 + lane;
        #pragma unroll
        for (int j = 0; j < TOPK; ++j)
            pc[((size_t)row * NCHUNK + mc) * TOPK + j] = bv[j];
    }
}

// ============ finalize: top-12 of 280 keys, EXACT fp32 refine, top-5 + softmax + blend ============
__global__ void finalize_kernel(const float* __restrict__ h, const float* __restrict__ db,
                                const float* __restrict__ alpha_p,
                                const unsigned* __restrict__ pc,
                                const float* __restrict__ inv_db,
                                float* __restrict__ out) {
    const int b    = blockIdx.x;
    const int tid  = threadIdx.x;
    const int lane = tid & 63;
    const int wv   = tid >> 6;
    const int NC   = NCHUNK * TOPK;   // 280

    __shared__ int   fid[NFIN];
    __shared__ float fsim[NFIN];
    __shared__ float invh_s;
    __shared__ float mu_s[TOPK];
    __shared__ int   id_s[TOPK];

    if (wv == 0) {
        const unsigned* cp = pc + (size_t)b * NC;
        unsigned v[5];
        #pragma unroll
        for (int j = 0; j < 5; ++j) {
            const int c = lane + j * 64;
            v[j] = (c < NC) ? cp[c] : 0u;
        }
        for (int it = 0; it < NFIN; ++it) {
            unsigned m = v[0];
            #pragma unroll
            for (int j = 1; j < 5; ++j) m = v[j] > m ? v[j] : m;
            #pragma unroll
            for (int sh = 1; sh < 64; sh <<= 1) {
                const unsigned o = (unsigned)__shfl_xor((int)m, sh);
                m = o > m ? o : m;
            }
            if (lane == 0) {
                int gi = (int)(m & 0xFFFFu);
                fid[it] = gi < DB_N ? gi : DB_N - 1;
            }
            #pragma unroll
            for (int j = 0; j < 5; ++j) if (v[j] == m) v[j] = 0u;
        }
    } else if (wv == 1) {
        const float* hr = h + (size_t)b * DIM;
        const float4 a = *(const float4*)(hr + lane * 8);
        const float4 c = *(const float4*)(hr + lane * 8 + 4);
        float ss = a.x*a.x + a.y*a.y + a.z*a.z + a.w*a.w
                 + c.x*c.x + c.y*c.y + c.z*c.z + c.w*c.w;
        #pragma unroll
        for (int off = 1; off < 64; off <<= 1) ss += __shfl_xor(ss, off);
        if (lane == 0) invh_s = 1.0f / fmaxf(sqrtf(ss), 1e-12f);
    }
    __syncthreads();

    const float* hr = h + (size_t)b * DIM;
    for (int f = wv; f < NFIN; f += 4) {
        const int gi = fid[f];
        const float* dr = db + (size_t)gi * DIM;
        const float4 ha = *(const float4*)(hr + lane * 8);
        const float4 hb = *(const float4*)(hr + lane * 8 + 4);
        const float4 da = *(const float4*)(dr + lane * 8);
        const float4 dc = *(const float4*)(dr + lane * 8 + 4);
        float d = ha.x*da.x + ha.y*da.y + ha.z*da.z + ha.w*da.w
                + hb.x*dc.x + hb.y*dc.y + hb.z*dc.z + hb.w*dc.w;
        #pragma unroll
        for (int off = 1; off < 64; off <<= 1) d += __shfl_xor(d, off);
        if (lane == 0) fsim[f] = d * invh_s * inv_db[gi];
    }
    __syncthreads();

    if (tid == 0) {
        bool used[NFIN];
        #pragma unroll
        for (int j = 0; j < NFIN; ++j) used[j] = false;
        float bv[TOPK]; int bi[TOPK];
        for (int it = 0; it < TOPK; ++it) {
            float m = -3.0e38f; int mj = 0, mi = 0x7fffffff;
            for (int j = 0; j < NFIN; ++j) {
                if (used[j]) continue;
                if (fsim[j] > m || (fsim[j] == m && fid[j] < mi)) {
                    m = fsim[j]; mj = j; mi = fid[j];
                }
            }
            used[mj] = true; bv[it] = m; bi[it] = mi;
        }
        float ssum = 0.f, w[TOPK];
        #pragma unroll
        for (int j = 0; j < TOPK; ++j) { w[j] = expf(bv[j] - bv[0]); ssum += w[j]; }
        #pragma unroll
        for (int j = 0; j < TOPK; ++j) { mu_s[j] = w[j] / ssum; id_s[j] = bi[j]; }
    }
    __syncthreads();

    const float a = 1.0f / (1.0f + expf(-alpha_p[0]));
    for (int d = tid; d < DIM; d += 256) {
        float r = 0.f;
        #pragma unroll
        for (int j = 0; j < TOPK; ++j) r += mu_s[j] * db[(size_t)id_s[j] * DIM + d];
        out[(size_t)b * DIM + d] = a * h[(size_t)b * DIM + d] + (1.f - a) * r;
    }
}

extern "C" void kernel_launch(void* const* d_in, const int* in_sizes, int n_in,
                              void* d_out, int out_size, void* d_ws, size_t ws_size,
                              hipStream_t stream) {
    const float* h     = (const float*)d_in[0];
    const float* db    = (const float*)d_in[1];
    const float* alpha = (const float*)d_in[2];
    float* out = (float*)d_out;

    const size_t dbzf_bytes = (size_t)PADN * DIM;        // 25,690,112
    const size_t hzf_bytes  = (size_t)BATCH * DIM;       //  1,048,576
    const size_t inv_bytes  = (size_t)PADN * 4;          //    200,704
    // pc: 2048*56*5*4 = 2,293,760  -> total ~29.2MB

    unsigned char* dbzf  = (unsigned char*)d_ws;
    unsigned char* hzf   = (unsigned char*)d_ws + dbzf_bytes;
    float*         invdb = (float*)((char*)d_ws + dbzf_bytes + hzf_bytes);
    unsigned*      pc    = (unsigned*)((char*)d_ws + dbzf_bytes + hzf_bytes + inv_bytes);

    convert_kernel<PADN><<<PADN / 4, 256, 0, stream>>>(db, dbzf, invdb, DB_N);
    convert_kernel<BATCH><<<BATCH / 4, 256, 0, stream>>>(h, hzf, nullptr, BATCH);
    sim_topk_kernel<<<16 * NCHUNK, 512, 0, stream>>>(hzf, dbzf, pc);
    finalize_kernel<<<BATCH, 256, 0, stream>>>(h, db, alpha, pc, invdb, out);
}